// Round 1
// baseline (542.797 us; speedup 1.0000x reference)
//
#include <hip/hip_runtime.h>
#include <hip/hip_bf16.h>

#define D_DIM 1024
#define NE 16
#define RK 64
#define NTOK 16384

typedef __bf16 bf16;
typedef __bf16 bf16x8 __attribute__((ext_vector_type(8)));
typedef __bf16 bf16x4 __attribute__((ext_vector_type(4)));
typedef float f32x4 __attribute__((ext_vector_type(4)));

__device__ __forceinline__ void gload16(const void* g, void* l) {
  __builtin_amdgcn_global_load_lds((const __attribute__((address_space(1))) unsigned int*)g,
                                   (__attribute__((address_space(3))) unsigned int*)l,
                                   16, 0, 0);
}

// ---------------- casts ----------------
__global__ void k_cast(const float* __restrict__ s, bf16* __restrict__ d, int n4) {
  int i = blockIdx.x * blockDim.x + threadIdx.x;
  if (i >= n4) return;
  float4 v = ((const float4*)s)[i];
  bf16x4 o = { (bf16)v.x, (bf16)v.y, (bf16)v.z, (bf16)v.w };
  ((bf16x4*)d)[i] = o;
}

// ---------------- G = W_gate @ W_enc  (fp64 partial sums, atomic combine) ----------------
__global__ void k_gmat(const float* __restrict__ Wg, const float* __restrict__ We,
                       float* __restrict__ G) {
  int d = blockIdx.x * 256 + threadIdx.x;
  int e = blockIdx.y;
  int j0 = blockIdx.z * 128;
  double acc = 0.0;
  for (int j = j0; j < j0 + 128; ++j)
    acc += (double)Wg[e * D_DIM + j] * (double)We[(size_t)j * D_DIM + d];
  atomicAdd(&G[e * D_DIM + d], (float)acc);
}

// ---------------- bgate[e] = W_gate[e,:] . b_enc ----------------
__global__ void k_bgate(const float* __restrict__ Wg, const float* __restrict__ be,
                        float* __restrict__ bg) {
  __shared__ double red[256];
  int e = blockIdx.x, t = threadIdx.x;
  double a = 0.0;
  for (int j = t; j < D_DIM; j += 256) a += (double)Wg[e * D_DIM + j] * (double)be[j];
  red[t] = a; __syncthreads();
  for (int s = 128; s > 0; s >>= 1) { if (t < s) red[t] += red[t + s]; __syncthreads(); }
  if (t == 0) bg[e] = (float)red[0];
}

// ---------------- gating: logits = x.G^T + bg, top-2, softmax, scatter ----------------
__global__ __launch_bounds__(256) void k_gate(const float* __restrict__ x,
                                              const float* __restrict__ G,
                                              const float* __restrict__ bg,
                                              const float* __restrict__ gamma,
                                              int* __restrict__ cnt,
                                              int* __restrict__ lists,
                                              float* __restrict__ wl) {
  int tok = blockIdx.x * 4 + (threadIdx.x >> 6);
  int lane = threadIdx.x & 63;
  const float* xr = x + (size_t)tok * D_DIM;
  double acc[NE];
#pragma unroll
  for (int e = 0; e < NE; ++e) acc[e] = 0.0;
  for (int i = lane; i < D_DIM; i += 64) {
    float xv = xr[i];
#pragma unroll
    for (int e = 0; e < NE; ++e) acc[e] += (double)xv * (double)G[e * D_DIM + i];
  }
#pragma unroll
  for (int off = 32; off > 0; off >>= 1) {
#pragma unroll
    for (int e = 0; e < NE; ++e) acc[e] += __shfl_xor(acc[e], off);
  }
  if (lane == 0) {
    double v1 = -1e300, v2 = -1e300; int i1 = 0, i2 = 0;
#pragma unroll
    for (int e = 0; e < NE; ++e) {
      double v = acc[e] + (double)bg[e];
      if (v > v1) { v2 = v1; i2 = i1; v1 = v; i1 = e; }
      else if (v > v2) { v2 = v; i2 = e; }
    }
    double e1 = exp(v2 - v1);
    double den = 1.0 + e1 + 1e-12;
    float w0 = (float)(1.0 / den) * gamma[i1];
    float w1 = (float)(e1 / den) * gamma[i2];
    int p0 = atomicAdd(&cnt[i1], 1);
    lists[(size_t)i1 * NTOK + p0] = tok;
    wl[(size_t)i1 * NTOK + p0] = w0;
    int p1 = atomicAdd(&cnt[NE + i2], 1);
    lists[(size_t)(NE + i2) * NTOK + p1] = tok;
    wl[(size_t)(NE + i2) * NTOK + p1] = w1;
  }
}

// ---------------- encoder GEMM: out = x @ W_enc^T + b (fp32) ; encb = bf16(out) ----------------
__global__ __launch_bounds__(256) void k_encgemm(const bf16* __restrict__ A,
                                                 const bf16* __restrict__ W,
                                                 const float* __restrict__ bias,
                                                 float* __restrict__ out,
                                                 bf16* __restrict__ encb) {
  __shared__ bf16 As[128 * 64];
  __shared__ bf16 Bs[128 * 64];
  const int K = D_DIM;
  int tid = threadIdx.x;
  int bn = blockIdx.x * 128;
  int bm = blockIdx.y * 128;
  int lane = tid & 63, wv = tid >> 6;
  int wm = (wv >> 1) * 64, wn = (wv & 1) * 64;
  int srow = tid >> 3, scol = (tid & 7) * 8;
  int fr = lane & 15, fk = (lane >> 4) * 8;
  f32x4 acc[4][4] = {};
  for (int k0 = 0; k0 < K; k0 += 64) {
    __syncthreads();
#pragma unroll
    for (int p = 0; p < 4; ++p) {
      int r = p * 32 + srow;
      gload16(A + (size_t)(bm + r) * K + k0 + scol, &As[r * 64 + scol]);
    }
#pragma unroll
    for (int p = 0; p < 4; ++p) {
      int r = p * 32 + srow;
      gload16(W + (size_t)(bn + r) * K + k0 + scol, &Bs[r * 64 + scol]);
    }
    __syncthreads();
#pragma unroll
    for (int kk = 0; kk < 2; ++kk) {
      bf16x8 af[4], bv[4];
#pragma unroll
      for (int m = 0; m < 4; ++m)
        af[m] = *(const bf16x8*)&As[(wm + m * 16 + fr) * 64 + kk * 32 + fk];
#pragma unroll
      for (int n = 0; n < 4; ++n)
        bv[n] = *(const bf16x8*)&Bs[(wn + n * 16 + fr) * 64 + kk * 32 + fk];
#pragma unroll
      for (int m = 0; m < 4; ++m)
#pragma unroll
        for (int n = 0; n < 4; ++n)
          acc[m][n] = __builtin_amdgcn_mfma_f32_16x16x32_bf16(af[m], bv[n], acc[m][n], 0, 0, 0);
    }
  }
  int rg = (lane >> 4) * 4;
#pragma unroll
  for (int n = 0; n < 4; ++n) {
    int col = bn + wn + n * 16 + fr;
    float bval = bias[col];
#pragma unroll
    for (int m = 0; m < 4; ++m) {
#pragma unroll
      for (int r = 0; r < 4; ++r) {
        int row = bm + wm + m * 16 + rg + r;
        float v = acc[m][n][r] + bval;
        out[(size_t)row * D_DIM + col] = v;
        encb[(size_t)row * D_DIM + col] = (bf16)v;
      }
    }
  }
}

// ---------------- expert kernel (one slot): gather 64 tokens, S=silu(enc U^T)*coef, out += S V^T ----------------
__global__ __launch_bounds__(256) void k_expert(const bf16* __restrict__ encb,
                                                const bf16* __restrict__ Ub,
                                                const bf16* __restrict__ Vb,
                                                const int* __restrict__ cnt,
                                                const int* __restrict__ lists,
                                                const float* __restrict__ wl,
                                                float* __restrict__ out, int slot) {
  int e = blockIdx.x;
  int c = cnt[slot * NE + e];
  int t0 = blockIdx.y * 64;
  if (t0 >= c) return;
  int nrows = c - t0; if (nrows > 64) nrows = 64;
  const int* tl = lists + (size_t)(slot * NE + e) * NTOK + t0;
  const float* wlp = wl + (size_t)(slot * NE + e) * NTOK + t0;

  __shared__ int toks[64];
  __shared__ float coefs[64];
  __shared__ bf16 As[64 * 64];
  __shared__ bf16 Us[64 * 64];
  __shared__ bf16 Ss[64 * 64];

  int tid = threadIdx.x;
  if (tid < 64) {
    int rr = tid < nrows ? tid : nrows - 1;
    toks[tid] = tl[rr];
    coefs[tid] = tid < nrows ? wlp[tid] : 0.0f;
  }
  __syncthreads();

  int lane = tid & 63, wv = tid >> 6;
  int srow = tid >> 3, scol = (tid & 7) * 8;
  int fr = lane & 15, fk = (lane >> 4) * 8;
  size_t tokA0 = (size_t)toks[srow] * D_DIM;
  size_t tokA1 = (size_t)toks[32 + srow] * D_DIM;
  const bf16* Ue = Ub + (size_t)e * RK * D_DIM;
  f32x4 acc1[4] = {};

  for (int k0 = 0; k0 < D_DIM; k0 += 64) {
    __syncthreads();
    gload16(encb + tokA0 + k0 + scol, &As[srow * 64 + scol]);
    gload16(encb + tokA1 + k0 + scol, &As[(32 + srow) * 64 + scol]);
    gload16(Ue + (size_t)srow * D_DIM + k0 + scol, &Us[srow * 64 + scol]);
    gload16(Ue + (size_t)(32 + srow) * D_DIM + k0 + scol, &Us[(32 + srow) * 64 + scol]);
    __syncthreads();
#pragma unroll
    for (int kk = 0; kk < 2; ++kk) {
      bf16x8 af = *(const bf16x8*)&As[(wv * 16 + fr) * 64 + kk * 32 + fk];
#pragma unroll
      for (int n = 0; n < 4; ++n) {
        bf16x8 bv = *(const bf16x8*)&Us[(n * 16 + fr) * 64 + kk * 32 + fk];
        acc1[n] = __builtin_amdgcn_mfma_f32_16x16x32_bf16(af, bv, acc1[n], 0, 0, 0);
      }
    }
  }
  int rg = (lane >> 4) * 4;
#pragma unroll
  for (int n = 0; n < 4; ++n)
#pragma unroll
    for (int r = 0; r < 4; ++r) {
      int row = wv * 16 + rg + r;
      float v = acc1[n][r];
      float s = v / (1.0f + __expf(-v));
      Ss[row * 64 + n * 16 + fr] = (bf16)(s * coefs[row]);
    }
  __syncthreads();
  bf16x8 a2[4][2];
#pragma unroll
  for (int m = 0; m < 4; ++m)
#pragma unroll
    for (int kk = 0; kk < 2; ++kk)
      a2[m][kk] = *(const bf16x8*)&Ss[(m * 16 + fr) * 64 + kk * 32 + fk];
  const bf16* Ve = Vb + (size_t)e * D_DIM * RK;
  int colbase = wv * 256;
  for (int nj = 0; nj < 16; ++nj) {
    int dcol = colbase + nj * 16 + fr;
    bf16x8 b0 = *(const bf16x8*)&Ve[(size_t)dcol * RK + fk];
    bf16x8 b1 = *(const bf16x8*)&Ve[(size_t)dcol * RK + 32 + fk];
#pragma unroll
    for (int m = 0; m < 4; ++m) {
      f32x4 a = {};
      a = __builtin_amdgcn_mfma_f32_16x16x32_bf16(a2[m][0], b0, a, 0, 0, 0);
      a = __builtin_amdgcn_mfma_f32_16x16x32_bf16(a2[m][1], b1, a, 0, 0, 0);
#pragma unroll
      for (int r = 0; r < 4; ++r) {
        int row = m * 16 + rg + r;
        if (row < nrows) {
          size_t off = (size_t)toks[row] * D_DIM + dcol;
          out[off] += a[r];
        }
      }
    }
  }
}

extern "C" void kernel_launch(void* const* d_in, const int* in_sizes, int n_in,
                              void* d_out, int out_size, void* d_ws, size_t ws_size,
                              hipStream_t stream) {
  const float* x   = (const float*)d_in[0];
  const float* We  = (const float*)d_in[1];
  const float* be  = (const float*)d_in[2];
  const float* Wg  = (const float*)d_in[3];
  const float* U   = (const float*)d_in[4];
  const float* V   = (const float*)d_in[5];
  const float* gam = (const float*)d_in[6];
  float* out = (float*)d_out;
  char* ws = (char*)d_ws;

  int*   cnt  = (int*)(ws + 0);                       // 128 B   (zeroed)
  float* G    = (float*)(ws + 256);                   // 64 KiB  (zeroed)
  float* bg   = (float*)(ws + 66048);                 // 64 B
  bf16*  xb   = (bf16*)(ws + 131072);                 // 32 MiB
  bf16*  encb = (bf16*)(ws + 131072 + 33554432);      // 32 MiB
  bf16*  Wb   = (bf16*)(ws + 131072 + 2 * 33554432);  // 2 MiB
  bf16*  Ubf  = (bf16*)(ws + 131072 + 2 * 33554432 + 2097152);
  bf16*  Vbf  = (bf16*)(ws + 131072 + 2 * 33554432 + 2 * 2097152);
  int*   lists= (int*)(ws + 131072 + 2 * 33554432 + 3 * 2097152);
  float* wl   = (float*)(ws + 131072 + 2 * 33554432 + 4 * 2097152);

  hipMemsetAsync(ws, 0, 66048, stream);

  k_cast<<<16384, 256, 0, stream>>>(x, xb, 16777216 / 4);
  k_cast<<<1024, 256, 0, stream>>>(We, Wb, 1048576 / 4);
  k_cast<<<1024, 256, 0, stream>>>(U, Ubf, 1048576 / 4);
  k_cast<<<1024, 256, 0, stream>>>(V, Vbf, 1048576 / 4);

  dim3 gg(4, 16, 8);
  k_gmat<<<gg, 256, 0, stream>>>(Wg, We, G);
  k_bgate<<<16, 256, 0, stream>>>(Wg, be, bg);
  k_gate<<<4096, 256, 0, stream>>>(x, G, bg, gam, cnt, lists, wl);

  dim3 ge(8, 128);
  k_encgemm<<<ge, 256, 0, stream>>>(xb, Wb, be, out, encb);

  dim3 gx(16, 256);
  k_expert<<<gx, 256, 0, stream>>>(encb, Ubf, Vbf, cnt, lists, wl, out, 0);
  k_expert<<<gx, 256, 0, stream>>>(encb, Ubf, Vbf, cnt, lists, wl, out, 1);
}

// Round 3
// 471.792 us; speedup vs baseline: 1.1505x; 1.1505x over previous
//
#include <hip/hip_runtime.h>
#include <hip/hip_bf16.h>

#define D_DIM 1024
#define NE 16
#define RK 64
#define NTOK 16384

typedef __bf16 bf16;
typedef __bf16 bf16x8 __attribute__((ext_vector_type(8)));
typedef __bf16 bf16x4 __attribute__((ext_vector_type(4)));
typedef float f32x4 __attribute__((ext_vector_type(4)));

__device__ __forceinline__ void gload16(const void* g, void* l) {
  __builtin_amdgcn_global_load_lds((const __attribute__((address_space(1))) unsigned int*)g,
                                   (__attribute__((address_space(3))) unsigned int*)l,
                                   16, 0, 0);
}

// ---------------- casts (weights only) ----------------
__global__ void k_cast(const float* __restrict__ s, bf16* __restrict__ d, int n4) {
  int i = blockIdx.x * blockDim.x + threadIdx.x;
  if (i >= n4) return;
  float4 v = ((const float4*)s)[i];
  bf16x4 o = { (bf16)v.x, (bf16)v.y, (bf16)v.z, (bf16)v.w };
  ((bf16x4*)d)[i] = o;
}

// ---------------- G = W_gate @ W_enc  (fp64 partial sums, atomic combine) ----------------
__global__ void k_gmat(const float* __restrict__ Wg, const float* __restrict__ We,
                       float* __restrict__ G) {
  int d = blockIdx.x * 256 + threadIdx.x;
  int e = blockIdx.y;
  int j0 = blockIdx.z * 128;
  double acc = 0.0;
  for (int j = j0; j < j0 + 128; ++j)
    acc += (double)Wg[e * D_DIM + j] * (double)We[(size_t)j * D_DIM + d];
  atomicAdd(&G[e * D_DIM + d], (float)acc);
}

// ---------------- bgate[e] = W_gate[e,:] . b_enc ----------------
__global__ void k_bgate(const float* __restrict__ Wg, const float* __restrict__ be,
                        float* __restrict__ bg) {
  __shared__ double red[256];
  int e = blockIdx.x, t = threadIdx.x;
  double a = 0.0;
  for (int j = t; j < D_DIM; j += 256) a += (double)Wg[e * D_DIM + j] * (double)be[j];
  red[t] = a; __syncthreads();
  for (int s = 128; s > 0; s >>= 1) { if (t < s) red[t] += red[t + s]; __syncthreads(); }
  if (t == 0) bg[e] = (float)red[0];
}

// ---------------- fused gating + x->bf16 cast ----------------
// G (16x1024 fp32, 64KB) staged in LDS once per block. 16 tokens/block,
// 4 tokens/wave processed simultaneously (G LDS reads amortized 4x).
// NOTE (R2 bug fix): stage loop stride is 1024 floats/iter (256 thr x 4 floats),
// NOT 4096 — previous version left 3/4 of Gs uninitialized.
__global__ __launch_bounds__(256) void k_gatecast(const float* __restrict__ x,
                                                  const float* __restrict__ G,
                                                  const float* __restrict__ bg,
                                                  const float* __restrict__ gamma,
                                                  bf16* __restrict__ xb,
                                                  int* __restrict__ cnt,
                                                  int* __restrict__ lists,
                                                  float* __restrict__ wl) {
  __shared__ float Gs[NE * D_DIM];
  int tid = threadIdx.x;
#pragma unroll
  for (int i = 0; i < 16; ++i) {
    int off = i * 1024 + tid * 4;   // 256 threads x 16B = 4KB per iter, 16 iters = 64KB
    gload16(G + off, &Gs[off]);
  }
  __syncthreads();  // drains vmcnt (compiler emits vmcnt(0) before barrier)

  int wv = tid >> 6, lane = tid & 63;
  int tokbase = blockIdx.x * 16 + wv * 4;
  const float* xp = x + (size_t)tokbase * D_DIM;
  float acc[4][NE] = {};
#pragma unroll
  for (int it = 0; it < 4; ++it) {
    int d0 = it * 256 + lane * 4;
    float4 xa[4];
#pragma unroll
    for (int t = 0; t < 4; ++t) {
      xa[t] = *(const float4*)(xp + t * D_DIM + d0);
      bf16x4 o = { (bf16)xa[t].x, (bf16)xa[t].y, (bf16)xa[t].z, (bf16)xa[t].w };
      *(bf16x4*)(xb + (size_t)(tokbase + t) * D_DIM + d0) = o;
    }
#pragma unroll
    for (int e = 0; e < NE; ++e) {
      float4 g = *(const float4*)&Gs[e * D_DIM + d0];
#pragma unroll
      for (int t = 0; t < 4; ++t)
        acc[t][e] += xa[t].x * g.x + xa[t].y * g.y + xa[t].z * g.z + xa[t].w * g.w;
    }
  }
#pragma unroll
  for (int off = 32; off > 0; off >>= 1)
#pragma unroll
    for (int t = 0; t < 4; ++t)
#pragma unroll
      for (int e = 0; e < NE; ++e)
        acc[t][e] += __shfl_xor(acc[t][e], off);

  if (lane < 4) {
    int t = lane;
    int tok = tokbase + t;
    float v1 = -1e30f, v2 = -1e30f; int i1 = 0, i2 = 0;
#pragma unroll
    for (int e = 0; e < NE; ++e) {
      float v = acc[t][e] + bg[e];
      if (v > v1) { v2 = v1; i2 = i1; v1 = v; i1 = e; }
      else if (v > v2) { v2 = v; i2 = e; }
    }
    float e1 = expf(v2 - v1);
    float den = 1.0f + e1 + 1e-12f;
    float w0 = (1.0f / den) * gamma[i1];
    float w1 = (e1 / den) * gamma[i2];
    int p0 = atomicAdd(&cnt[i1], 1);
    lists[(size_t)i1 * NTOK + p0] = tok;
    wl[(size_t)i1 * NTOK + p0] = w0;
    int p1 = atomicAdd(&cnt[NE + i2], 1);
    lists[(size_t)(NE + i2) * NTOK + p1] = tok;
    wl[(size_t)(NE + i2) * NTOK + p1] = w1;
  }
}

// ---------------- encoder GEMM: out = x @ W_enc^T + b (fp32) ; encb = bf16(out) ----------------
__global__ __launch_bounds__(256) void k_encgemm(const bf16* __restrict__ A,
                                                 const bf16* __restrict__ W,
                                                 const float* __restrict__ bias,
                                                 float* __restrict__ out,
                                                 bf16* __restrict__ encb) {
  __shared__ bf16 As[128 * 64];
  __shared__ bf16 Bs[128 * 64];
  const int K = D_DIM;
  int tid = threadIdx.x;
  int bn = blockIdx.x * 128;
  int bm = blockIdx.y * 128;
  int lane = tid & 63, wv = tid >> 6;
  int wm = (wv >> 1) * 64, wn = (wv & 1) * 64;
  int srow = tid >> 3, scol = (tid & 7) * 8;
  int fr = lane & 15, fk = (lane >> 4) * 8;
  f32x4 acc[4][4] = {};
  for (int k0 = 0; k0 < K; k0 += 64) {
    __syncthreads();
#pragma unroll
    for (int p = 0; p < 4; ++p) {
      int r = p * 32 + srow;
      gload16(A + (size_t)(bm + r) * K + k0 + scol, &As[r * 64 + scol]);
    }
#pragma unroll
    for (int p = 0; p < 4; ++p) {
      int r = p * 32 + srow;
      gload16(W + (size_t)(bn + r) * K + k0 + scol, &Bs[r * 64 + scol]);
    }
    __syncthreads();
#pragma unroll
    for (int kk = 0; kk < 2; ++kk) {
      bf16x8 af[4], bv[4];
#pragma unroll
      for (int m = 0; m < 4; ++m)
        af[m] = *(const bf16x8*)&As[(wm + m * 16 + fr) * 64 + kk * 32 + fk];
#pragma unroll
      for (int n = 0; n < 4; ++n)
        bv[n] = *(const bf16x8*)&Bs[(wn + n * 16 + fr) * 64 + kk * 32 + fk];
#pragma unroll
      for (int m = 0; m < 4; ++m)
#pragma unroll
        for (int n = 0; n < 4; ++n)
          acc[m][n] = __builtin_amdgcn_mfma_f32_16x16x32_bf16(af[m], bv[n], acc[m][n], 0, 0, 0);
    }
  }
  int rg = (lane >> 4) * 4;
#pragma unroll
  for (int n = 0; n < 4; ++n) {
    int col = bn + wn + n * 16 + fr;
    float bval = bias[col];
#pragma unroll
    for (int m = 0; m < 4; ++m) {
#pragma unroll
      for (int r = 0; r < 4; ++r) {
        int row = bm + wm + m * 16 + rg + r;
        float v = acc[m][n][r] + bval;
        out[(size_t)row * D_DIM + col] = v;
        encb[(size_t)row * D_DIM + col] = (bf16)v;
      }
    }
  }
}

// ---------------- expert kernel (one slot): gather 64 tokens, S=silu(enc U^T)*coef, out += S V^T ----------------
__global__ __launch_bounds__(256) void k_expert(const bf16* __restrict__ encb,
                                                const bf16* __restrict__ Ub,
                                                const bf16* __restrict__ Vb,
                                                const int* __restrict__ cnt,
                                                const int* __restrict__ lists,
                                                const float* __restrict__ wl,
                                                float* __restrict__ out, int slot) {
  int e = blockIdx.x;
  int c = cnt[slot * NE + e];
  int t0 = blockIdx.y * 64;
  if (t0 >= c) return;
  int nrows = c - t0; if (nrows > 64) nrows = 64;
  const int* tl = lists + (size_t)(slot * NE + e) * NTOK + t0;
  const float* wlp = wl + (size_t)(slot * NE + e) * NTOK + t0;

  __shared__ int toks[64];
  __shared__ float coefs[64];
  __shared__ bf16 As[64 * 64];
  __shared__ bf16 Us[64 * 64];
  __shared__ bf16 Ss[64 * 64];

  int tid = threadIdx.x;
  if (tid < 64) {
    int rr = tid < nrows ? tid : nrows - 1;
    toks[tid] = tl[rr];
    coefs[tid] = tid < nrows ? wlp[tid] : 0.0f;
  }
  __syncthreads();

  int lane = tid & 63, wv = tid >> 6;
  int srow = tid >> 3, scol = (tid & 7) * 8;
  int fr = lane & 15, fk = (lane >> 4) * 8;
  size_t tokA0 = (size_t)toks[srow] * D_DIM;
  size_t tokA1 = (size_t)toks[32 + srow] * D_DIM;
  const bf16* Ue = Ub + (size_t)e * RK * D_DIM;
  f32x4 acc1[4] = {};

  for (int k0 = 0; k0 < D_DIM; k0 += 64) {
    __syncthreads();
    gload16(encb + tokA0 + k0 + scol, &As[srow * 64 + scol]);
    gload16(encb + tokA1 + k0 + scol, &As[(32 + srow) * 64 + scol]);
    gload16(Ue + (size_t)srow * D_DIM + k0 + scol, &Us[srow * 64 + scol]);
    gload16(Ue + (size_t)(32 + srow) * D_DIM + k0 + scol, &Us[(32 + srow) * 64 + scol]);
    __syncthreads();
#pragma unroll
    for (int kk = 0; kk < 2; ++kk) {
      bf16x8 af = *(const bf16x8*)&As[(wv * 16 + fr) * 64 + kk * 32 + fk];
#pragma unroll
      for (int n = 0; n < 4; ++n) {
        bf16x8 bv = *(const bf16x8*)&Us[(n * 16 + fr) * 64 + kk * 32 + fk];
        acc1[n] = __builtin_amdgcn_mfma_f32_16x16x32_bf16(af, bv, acc1[n], 0, 0, 0);
      }
    }
  }
  int rg = (lane >> 4) * 4;
#pragma unroll
  for (int n = 0; n < 4; ++n)
#pragma unroll
    for (int r = 0; r < 4; ++r) {
      int row = wv * 16 + rg + r;
      float v = acc1[n][r];
      float s = v / (1.0f + __expf(-v));
      Ss[row * 64 + n * 16 + fr] = (bf16)(s * coefs[row]);
    }
  __syncthreads();
  bf16x8 a2[4][2];
#pragma unroll
  for (int m = 0; m < 4; ++m)
#pragma unroll
    for (int kk = 0; kk < 2; ++kk)
      a2[m][kk] = *(const bf16x8*)&Ss[(m * 16 + fr) * 64 + kk * 32 + fk];
  const bf16* Ve = Vb + (size_t)e * D_DIM * RK;
  int colbase = wv * 256;
  for (int nj = 0; nj < 16; ++nj) {
    int dcol = colbase + nj * 16 + fr;
    bf16x8 b0 = *(const bf16x8*)&Ve[(size_t)dcol * RK + fk];
    bf16x8 b1 = *(const bf16x8*)&Ve[(size_t)dcol * RK + 32 + fk];
#pragma unroll
    for (int m = 0; m < 4; ++m) {
      f32x4 a = {};
      a = __builtin_amdgcn_mfma_f32_16x16x32_bf16(a2[m][0], b0, a, 0, 0, 0);
      a = __builtin_amdgcn_mfma_f32_16x16x32_bf16(a2[m][1], b1, a, 0, 0, 0);
#pragma unroll
      for (int r = 0; r < 4; ++r) {
        int row = m * 16 + rg + r;
        if (row < nrows) {
          size_t off = (size_t)toks[row] * D_DIM + dcol;
          out[off] += a[r];
        }
      }
    }
  }
}

extern "C" void kernel_launch(void* const* d_in, const int* in_sizes, int n_in,
                              void* d_out, int out_size, void* d_ws, size_t ws_size,
                              hipStream_t stream) {
  const float* x   = (const float*)d_in[0];
  const float* We  = (const float*)d_in[1];
  const float* be  = (const float*)d_in[2];
  const float* Wg  = (const float*)d_in[3];
  const float* U   = (const float*)d_in[4];
  const float* V   = (const float*)d_in[5];
  const float* gam = (const float*)d_in[6];
  float* out = (float*)d_out;
  char* ws = (char*)d_ws;

  int*   cnt  = (int*)(ws + 0);                       // 128 B   (zeroed)
  float* G    = (float*)(ws + 256);                   // 64 KiB  (zeroed)
  float* bg   = (float*)(ws + 66048);                 // 64 B
  bf16*  xb   = (bf16*)(ws + 131072);                 // 32 MiB
  bf16*  encb = (bf16*)(ws + 131072 + 33554432);      // 32 MiB
  bf16*  Wb   = (bf16*)(ws + 131072 + 2 * 33554432);  // 2 MiB
  bf16*  Ubf  = (bf16*)(ws + 131072 + 2 * 33554432 + 2097152);
  bf16*  Vbf  = (bf16*)(ws + 131072 + 2 * 33554432 + 2 * 2097152);
  int*   lists= (int*)(ws + 131072 + 2 * 33554432 + 3 * 2097152);
  float* wl   = (float*)(ws + 131072 + 2 * 33554432 + 4 * 2097152);

  hipMemsetAsync(ws, 0, 66048, stream);

  k_cast<<<1024, 256, 0, stream>>>(We, Wb, 1048576 / 4);
  k_cast<<<1024, 256, 0, stream>>>(U, Ubf, 1048576 / 4);
  k_cast<<<1024, 256, 0, stream>>>(V, Vbf, 1048576 / 4);

  dim3 gg(4, 16, 8);
  k_gmat<<<gg, 256, 0, stream>>>(Wg, We, G);
  k_bgate<<<16, 256, 0, stream>>>(Wg, be, bg);

  k_gatecast<<<1024, 256, 0, stream>>>(x, G, bg, gam, xb, cnt, lists, wl);

  dim3 ge(8, 128);
  k_encgemm<<<ge, 256, 0, stream>>>(xb, Wb, be, out, encb);

  dim3 gx(16, 256);
  k_expert<<<gx, 256, 0, stream>>>(encb, Ubf, Vbf, cnt, lists, wl, out, 0);
  k_expert<<<gx, 256, 0, stream>>>(encb, Ubf, Vbf, cnt, lists, wl, out, 1);
}